// Round 4
// baseline (524.949 us; speedup 1.0000x reference)
//
#include <hip/hip_runtime.h>

typedef __attribute__((ext_vector_type(8))) short bf16x8;
typedef __attribute__((ext_vector_type(4))) float f32x4;
typedef __attribute__((ext_vector_type(4))) int i32x4;

#define MFMA16(a,b,c) __builtin_amdgcn_mfma_f32_16x16x32_bf16(a,b,c,0,0,0)

#define SCALE 0.1767766952966369f   // 32^-0.5

static __device__ __forceinline__ f32x4 zero4(){
    f32x4 z = {0.f,0.f,0.f,0.f};
    return z;
}

static __device__ __forceinline__ float bf2f(unsigned short u){
    unsigned int x = ((unsigned int)u) << 16;
    return __builtin_bit_cast(float, x);
}
static __device__ __forceinline__ unsigned short f2bf(float f){
    __bf16 b = (__bf16)f;
    return __builtin_bit_cast(unsigned short, b);
}

// ---------------- prep kernels (fp32 inputs -> bf16 internals) ----------------
__global__ __launch_bounds__(256) void k_prep_wt(const float* __restrict__ qkv_w,
                                                 unsigned short* __restrict__ wt){
    int i = blockIdx.x*256 + threadIdx.x;           // wt[n][k] = qkv_w[k][n], 576x192
    if (i < 576*192){ int n = i/192, kk = i%192; wt[i] = f2bf(qkv_w[kk*576 + n]); }
}
__global__ __launch_bounds__(256) void k_prep_pwt(const float* __restrict__ proj_w,
                                                  unsigned short* __restrict__ pwt){
    int i = blockIdx.x*256 + threadIdx.x;           // pwt[n][k] = proj_w[k][n], 192x192
    if (i < 192*192){ int n = i/192, kk = i%192; pwt[i] = f2bf(proj_w[kk*192 + n]); }
}
// bias[h][q][c] (c padded to 352) = rpb_table[RPI(q,c)*6 + h]
__global__ __launch_bounds__(256) void k_prep_bias(const float* __restrict__ rpb,
                                                   unsigned short* __restrict__ bias){
    int i = blockIdx.x*256 + threadIdx.x;
    if (i >= 6*343*352) return;
    int h = i / (343*352); int rem = i % (343*352);
    int qi = rem / 352, ci = rem % 352;
    unsigned short v = 0;
    if (ci < 343){
        // meshgrid 'xy': coord0 = (p/7)%7, coord1 = p/49, coord2 = p%7
        int qa=qi/49, qr=qi%49, qb=qr/7, qc=qr%7;
        int ka=ci/49, kr=ci%49, kb=kr/7, kc=kr%7;
        int idx = 169*(qb-kb+6) + 13*(qa-ka+6) + (qc-kc+6);
        v = f2bf(rpb[idx*6 + h]);
    }
    bias[i] = v;
}

// ---------------- qkv projection ----------------
// x[87808][192] (fp32) @ qkv_w[192][576] -> q/k [b,h,343,32] bf16 (q pre-scaled), v^T [b,h,32,344]
__global__ __launch_bounds__(256) void k_qkv(const float* __restrict__ x,
                                             const unsigned short* __restrict__ wt,
                                             unsigned short* __restrict__ q,
                                             unsigned short* __restrict__ k,
                                             unsigned short* __restrict__ vt){
    __shared__ __attribute__((aligned(16))) unsigned short Bs[576*40];  // [n][k-chunk] pitch 40
    const int tid  = threadIdx.x;
    const int wid  = tid>>6, lane = tid&63, quad = lane>>4, l15 = lane&15;
    const int m0   = blockIdx.x*64;
    f32x4 acc[36];
    #pragma unroll
    for (int st=0; st<36; ++st) acc[st] = zero4();
    const float* arow = x + (m0 + wid*16 + l15)*192 + quad*8;
    for (int k0=0; k0<192; k0+=32){
        __syncthreads();
        for (int i=tid; i<2304; i+=256){                 // 576 rows x 4 chunks of 8
            int rr=i>>2, cc=(i&3)<<3;
            *(i32x4*)&Bs[rr*40+cc] = *(const i32x4*)(wt + rr*192 + k0 + cc);
        }
        __syncthreads();
        f32x4 af0 = *(const f32x4*)(arow + k0);
        f32x4 af1 = *(const f32x4*)(arow + k0 + 4);
        bf16x8 a;
        #pragma unroll
        for (int j=0; j<4; ++j){
            a[j]   = (short)f2bf(af0[j]);
            a[4+j] = (short)f2bf(af1[j]);
        }
        #pragma unroll
        for (int st=0; st<36; ++st){
            bf16x8 b = *(const bf16x8*)&Bs[(st*16+l15)*40 + quad*8];
            acc[st] = MFMA16(a, b, acc[st]);
        }
    }
    #pragma unroll
    for (int r=0; r<4; ++r){
        int tm = m0 + wid*16 + quad*4 + r;               // global token row
        int bb = tm/343, tt = tm%343;
        #pragma unroll
        for (int st=0; st<36; ++st){
            const int f0 = st*16;
            const int s  = f0/192, h = (f0%192)>>5, d0 = f0&31;
            int d = d0 + l15;
            float v = acc[st][r];
            if (s==0)      q[((bb*6+h)*343 + tt)*32 + d] = f2bf(v*SCALE);
            else if (s==1) k[((bb*6+h)*343 + tt)*32 + d] = f2bf(v);
            else           vt[((bb*6+h)*32 + d)*344 + tt] = f2bf(v);
        }
    }
}

// ---------------- fused attention ----------------
__global__ __launch_bounds__(256) void k_attn(const unsigned short* __restrict__ q,
                                              const unsigned short* __restrict__ kg,
                                              const unsigned short* __restrict__ vt,
                                              const float* __restrict__ mask,
                                              const unsigned short* __restrict__ bias,
                                              unsigned short* __restrict__ ao){
    __shared__ __attribute__((aligned(16))) unsigned short Ks[352*40];       // [key][k] pitch 40
    __shared__ __attribute__((aligned(16))) unsigned short Vs[32*344 + 64];  // [d][key] pitch 344
    __shared__ __attribute__((aligned(16))) unsigned short Pb[4*2*640];      // per-wave dbuf 16x40
    const int tid = threadIdx.x;
    const int wid = tid>>6, lane = tid&63, quad = lane>>4, l15 = lane&15;
    const int idx = blockIdx.x;
    const int w = idx/24, sub = idx%24, g = sub/6, h = sub%6, b = g*64 + w;  // group same-mask blocks
    const int bh = b*6 + h;
    const unsigned short* kb  = kg + bh*10976;
    const unsigned short* vb  = vt + bh*11008;
    const unsigned short* qb  = q  + bh*10976;
    const float*          mw  = mask + w*117649;
    const unsigned short* bhp = bias + h*120736;

    for (int i=tid; i<1372; i+=256){                     // K: 343x32
        int rr=i>>2, cc=(i&3)<<3;
        *(i32x4*)&Ks[rr*40+cc] = *(const i32x4*)(kb + rr*32 + cc);
    }
    for (int i=tid; i<1376; i+=256)                      // V^T: 32x344 straight copy
        *(i32x4*)&Vs[i*8] = *(const i32x4*)(vb + i*8);
    if (tid < 64) Vs[32*344 + tid] = 0;
    __syncthreads();

    for (int chunk=wid; chunk<22; chunk+=4){             // 16-row Q strips, waves independent
        int qrow = chunk*16 + l15; if (qrow > 342) qrow = 342;   // stay inside this bh's q slice
        bf16x8 a = *(const bf16x8*)(qb + qrow*32 + quad*8);
        f32x4 s[22];
        #pragma unroll
        for (int t=0; t<22; ++t){
            bf16x8 bb = *(const bf16x8*)&Ks[(t*16+l15)*40 + quad*8];
            s[t] = MFMA16(a, bb, zero4());
        }
        const int row0 = chunk*16 + quad*4;
        #pragma unroll
        for (int r=0; r<4; ++r){
            int row = row0 + r; int rowc = row>342 ? 342 : row;
            const float*          mrow = mw  + rowc*343;
            const unsigned short* brow = bhp + rowc*352;
            #pragma unroll
            for (int t=0; t<22; ++t){
                int col  = t*16 + l15;
                int colc = col>342 ? 342 : col;
                s[t][r] += mrow[colc] + bf2f(brow[col]);
            }
        }
        if (l15 >= 7){                                   // columns 343..351 -> -inf
            #pragma unroll
            for (int r=0; r<4; ++r) s[21][r] = -1e30f;
        }
        f32x4 mx, sm, inv;
        #pragma unroll
        for (int r=0; r<4; ++r){
            float m = s[0][r];
            #pragma unroll
            for (int t=1; t<22; ++t) m = fmaxf(m, s[t][r]);
            mx[r] = m;
        }
        #pragma unroll
        for (int d=1; d<16; d<<=1){
            #pragma unroll
            for (int r=0; r<4; ++r) mx[r] = fmaxf(mx[r], __shfl_xor(mx[r], d));
        }
        #pragma unroll
        for (int r=0; r<4; ++r){
            float acc = 0.f;
            #pragma unroll
            for (int t=0; t<22; ++t){ float e = __expf(s[t][r]-mx[r]); s[t][r]=e; acc += e; }
            sm[r] = acc;
        }
        #pragma unroll
        for (int d=1; d<16; d<<=1){
            #pragma unroll
            for (int r=0; r<4; ++r) sm[r] += __shfl_xor(sm[r], d);
        }
        #pragma unroll
        for (int r=0; r<4; ++r) inv[r] = 1.0f / sm[r];

        f32x4 o0 = zero4(), o1 = zero4();
        unsigned short* pw0 = Pb + wid*1280;
        #pragma unroll
        for (int ks=0; ks<11; ++ks){                     // P(C-layout) -> LDS -> A-layout, 32 keys/step
            unsigned short* pw = pw0 + (ks&1)*640;
            #pragma unroll
            for (int tt=0; tt<2; ++tt){
                int t = ks*2+tt;
                #pragma unroll
                for (int r=0; r<4; ++r)
                    pw[(quad*4+r)*40 + tt*16 + l15] = f2bf(s[t][r]*inv[r]);
            }
            asm volatile("s_waitcnt lgkmcnt(0)" ::: "memory");
            bf16x8 ap = *(const bf16x8*)&pw[l15*40 + quad*8];
            bf16x8 v0 = *(const bf16x8*)&Vs[l15*344      + ks*32 + quad*8];
            bf16x8 v1 = *(const bf16x8*)&Vs[(16+l15)*344 + ks*32 + quad*8];
            o0 = MFMA16(ap, v0, o0);
            o1 = MFMA16(ap, v1, o1);
        }
        #pragma unroll
        for (int r=0; r<4; ++r){
            int nt = row0 + r;
            if (nt < 343){
                unsigned short* dst = ao + (b*343 + nt)*192 + h*32;
                dst[l15]    = f2bf(o0[r]);
                dst[16+l15] = f2bf(o1[r]);
            }
        }
    }
}

// ---------------- output projection (fp32 output!) ----------------
__global__ __launch_bounds__(256) void k_proj(const unsigned short* __restrict__ ao,
                                              const unsigned short* __restrict__ pwt,
                                              const float* __restrict__ pbias,
                                              float* __restrict__ out){
    const int tid = threadIdx.x, wid = tid>>6, lane = tid&63, quad = lane>>4, l15 = lane&15;
    const int m0 = blockIdx.x*64 + wid*16;
    f32x4 acc[12];
    #pragma unroll
    for (int st=0; st<12; ++st) acc[st] = zero4();
    float bl[12];
    #pragma unroll
    for (int st=0; st<12; ++st) bl[st] = pbias[st*16 + l15];
    const unsigned short* arow = ao + (m0 + l15)*192 + quad*8;
    for (int k0=0; k0<192; k0+=32){
        bf16x8 a = *(const bf16x8*)(arow + k0);
        #pragma unroll
        for (int st=0; st<12; ++st){
            bf16x8 bb = *(const bf16x8*)(pwt + (st*16+l15)*192 + k0 + quad*8);
            acc[st] = MFMA16(a, bb, acc[st]);
        }
    }
    #pragma unroll
    for (int r=0; r<4; ++r){
        int tm = m0 + quad*4 + r;
        #pragma unroll
        for (int st=0; st<12; ++st)
            out[tm*192 + st*16 + l15] = acc[st][r] + bl[st];
    }
}

extern "C" void kernel_launch(void* const* d_in, const int* in_sizes, int n_in,
                              void* d_out, int out_size, void* d_ws, size_t ws_size,
                              hipStream_t stream){
    const float* x     = (const float*)d_in[0];
    const float* mask  = (const float*)d_in[1];
    const float* qkv_w = (const float*)d_in[2];
    const float* rpb   = (const float*)d_in[3];
    const float* projw = (const float*)d_in[4];
    const float* projb = (const float*)d_in[5];
    float* out = (float*)d_out;
    unsigned short* ws  = (unsigned short*)d_ws;

    unsigned short* wt   = ws;                 // 110592
    unsigned short* pwt  = wt   + 110592;      // 36864
    unsigned short* bias = pwt  + 36864;       // 724416
    unsigned short* q    = bias + 724416;      // 16859136
    unsigned short* k    = q    + 16859136;    // 16859136
    unsigned short* vt   = k    + 16859136;    // 16908288 (pitch 344)
    unsigned short* ao   = vt   + 16908288;    // 16859136   total ~136.7 MB

    hipLaunchKernelGGL(k_prep_wt,   dim3(432),  dim3(256), 0, stream, qkv_w, wt);
    hipLaunchKernelGGL(k_prep_pwt,  dim3(144),  dim3(256), 0, stream, projw, pwt);
    hipLaunchKernelGGL(k_prep_bias, dim3(2830), dim3(256), 0, stream, rpb, bias);
    hipLaunchKernelGGL(k_qkv,       dim3(1372), dim3(256), 0, stream, x, wt, q, k, vt);
    hipLaunchKernelGGL(k_attn,      dim3(1536), dim3(256), 0, stream, q, k, vt, mask, bias, ao);
    hipLaunchKernelGGL(k_proj,      dim3(1372), dim3(256), 0, stream, ao, pwt, projb, out);
}

// Round 5
// 459.465 us; speedup vs baseline: 1.1425x; 1.1425x over previous
//
#include <hip/hip_runtime.h>

typedef __attribute__((ext_vector_type(8))) short bf16x8;
typedef __attribute__((ext_vector_type(4))) float f32x4;
typedef __attribute__((ext_vector_type(4))) int i32x4;

#define MFMA16(a,b,c) __builtin_amdgcn_mfma_f32_16x16x32_bf16(a,b,c,0,0,0)

#define SCALE 0.1767766952966369f   // 32^-0.5

static __device__ __forceinline__ f32x4 zero4(){
    f32x4 z = {0.f,0.f,0.f,0.f};
    return z;
}
static __device__ __forceinline__ float bf2f(unsigned short u){
    unsigned int x = ((unsigned int)u) << 16;
    return __builtin_bit_cast(float, x);
}
static __device__ __forceinline__ unsigned short f2bf(float f){
    __bf16 b = (__bf16)f;
    return __builtin_bit_cast(unsigned short, b);
}
// LDS-only barrier: waits for LDS ops but leaves global loads in flight
// (avoids the vmcnt(0) drain __syncthreads() would emit).
static __device__ __forceinline__ void bar_lds(){
    asm volatile("s_waitcnt lgkmcnt(0)" ::: "memory");
    __builtin_amdgcn_s_barrier();
}

// ---------------- prep kernels (fp32 inputs -> bf16 internals) ----------------
__global__ __launch_bounds__(256) void k_prep_wt(const float* __restrict__ qkv_w,
                                                 unsigned short* __restrict__ wt){
    int i = blockIdx.x*256 + threadIdx.x;           // wt[n][k] = qkv_w[k][n], 576x192
    if (i < 576*192){ int n = i/192, kk = i%192; wt[i] = f2bf(qkv_w[kk*576 + n]); }
}
__global__ __launch_bounds__(256) void k_prep_pwt(const float* __restrict__ proj_w,
                                                  unsigned short* __restrict__ pwt){
    int i = blockIdx.x*256 + threadIdx.x;           // pwt[n][k] = proj_w[k][n], 192x192
    if (i < 192*192){ int n = i/192, kk = i%192; pwt[i] = f2bf(proj_w[kk*192 + n]); }
}
// bias[h][q][c] (c padded to 352) = rpb_table[RPI(q,c)*6 + h]
__global__ __launch_bounds__(256) void k_prep_bias(const float* __restrict__ rpb,
                                                   unsigned short* __restrict__ bias){
    int i = blockIdx.x*256 + threadIdx.x;
    if (i >= 6*343*352) return;
    int h = i / (343*352); int rem = i % (343*352);
    int qi = rem / 352, ci = rem % 352;
    unsigned short v = 0;
    if (ci < 343){
        // meshgrid 'xy': coord0 = (p/7)%7, coord1 = p/49, coord2 = p%7
        int qa=qi/49, qr=qi%49, qb=qr/7, qc=qr%7;
        int ka=ci/49, kr=ci%49, kb=kr/7, kc=kr%7;
        int idx = 169*(qb-kb+6) + 13*(qa-ka+6) + (qc-kc+6);
        v = f2bf(rpb[idx*6 + h]);
    }
    bias[i] = v;
}

// ---------------- qkv projection (pipelined) ----------------
// Block: 128 token-rows x 192 out-cols (nq selects q/k/v third). Double-buffered
// LDS B chunks; raw barrier keeps prefetch loads in flight across it.
__global__ __launch_bounds__(256, 3) void k_qkv(const float* __restrict__ x,
                                                const unsigned short* __restrict__ wt,
                                                unsigned short* __restrict__ q,
                                                unsigned short* __restrict__ k,
                                                unsigned short* __restrict__ v){
    __shared__ __attribute__((aligned(16))) unsigned short Bs[2][192*40];   // 2 x 15 KB
    const int tid = threadIdx.x;
    const int wid = tid>>6, lane = tid&63, quad = lane>>4, l15 = lane&15;
    const int nq = blockIdx.x % 3;          // 0=q, 1=k, 2=v (cols nq*192..+192)
    const int mg = blockIdx.x / 3;          // rows mg*128..+128
    const int srr = tid>>2, scc = (tid&3)<<3;   // this thread stages rows srr, srr+64, srr+128

    f32x4 acc[24];
    #pragma unroll
    for (int i=0;i<24;++i) acc[i] = zero4();

    const unsigned short* wtb = wt + nq*192*192;
    i32x4 s0, s1, s2;
    s0 = *(const i32x4*)(wtb + (srr      )*192 + scc);
    s1 = *(const i32x4*)(wtb + (srr +  64)*192 + scc);
    s2 = *(const i32x4*)(wtb + (srr + 128)*192 + scc);

    const int r0 = mg*128 + wid*32 + l15;                // mtile0 row; mtile1 = +16
    const float* xp0 = x + (long)r0*192 + quad*8;
    const float* xp1 = xp0 + 16*192;
    f32x4 xa0 = *(const f32x4*)(xp0);
    f32x4 xa1 = *(const f32x4*)(xp0+4);
    f32x4 xb0 = *(const f32x4*)(xp1);
    f32x4 xb1 = *(const f32x4*)(xp1+4);

    for (int k0=0; k0<6; ++k0){
        unsigned short* B = &Bs[k0&1][0];
        *(i32x4*)&B[(srr      )*40 + scc] = s0;
        *(i32x4*)&B[(srr +  64)*40 + scc] = s1;
        *(i32x4*)&B[(srr + 128)*40 + scc] = s2;
        if (k0 < 5){                                      // prefetch next B chunk
            const unsigned short* wn = wtb + (k0+1)*32;
            s0 = *(const i32x4*)(wn + (srr      )*192 + scc);
            s1 = *(const i32x4*)(wn + (srr +  64)*192 + scc);
            s2 = *(const i32x4*)(wn + (srr + 128)*192 + scc);
        }
        bf16x8 a0, a1;
        #pragma unroll
        for (int j=0;j<4;++j){
            a0[j] = (short)f2bf(xa0[j]); a0[4+j] = (short)f2bf(xa1[j]);
            a1[j] = (short)f2bf(xb0[j]); a1[4+j] = (short)f2bf(xb1[j]);
        }
        if (k0 < 5){                                      // prefetch next x
            xa0 = *(const f32x4*)(xp0 + (k0+1)*32);
            xa1 = *(const f32x4*)(xp0 + (k0+1)*32 + 4);
            xb0 = *(const f32x4*)(xp1 + (k0+1)*32);
            xb1 = *(const f32x4*)(xp1 + (k0+1)*32 + 4);
        }
        bar_lds();                                        // LDS writes visible; vmem stays in flight
        #pragma unroll
        for (int nt=0; nt<12; ++nt){
            bf16x8 b = *(const bf16x8*)&B[(nt*16+l15)*40 + quad*8];
            acc[nt]    = MFMA16(a0, b, acc[nt]);
            acc[12+nt] = MFMA16(a1, b, acc[12+nt]);
        }
    }

    unsigned short* dst = (nq==0) ? q : (nq==1) ? k : v;
    const float mul = (nq==0) ? SCALE : 1.0f;
    #pragma unroll
    for (int mt=0; mt<2; ++mt){
        #pragma unroll
        for (int r=0; r<4; ++r){
            int tm = mg*128 + wid*32 + mt*16 + quad*4 + r;
            int bb = tm/343, tt = tm%343;
            #pragma unroll
            for (int nt=0; nt<12; ++nt){
                int cc = nt*16 + l15;                     // 0..191 within this third
                int h = cc>>5, d = cc&31;
                dst[((bb*6+h)*343 + tt)*32 + d] = f2bf(acc[mt*12+nt][r]*mul);
            }
        }
    }
}

// ---------------- fused attention ----------------
__global__ __launch_bounds__(256) void k_attn(const unsigned short* __restrict__ q,
                                              const unsigned short* __restrict__ kg,
                                              const unsigned short* __restrict__ vg,
                                              const float* __restrict__ mask,
                                              const unsigned short* __restrict__ bias,
                                              unsigned short* __restrict__ ao){
    __shared__ __attribute__((aligned(16))) unsigned short Ks[352*40];       // [key][k] pitch 40
    __shared__ __attribute__((aligned(16))) unsigned short Vs[32*344 + 64];  // [d][key] pitch 344
    __shared__ __attribute__((aligned(16))) unsigned short Pb[4*2*640];      // per-wave dbuf 16x40
    const int tid = threadIdx.x;
    const int wid = tid>>6, lane = tid&63, quad = lane>>4, l15 = lane&15;
    const int idx = blockIdx.x;
    const int w = idx/24, sub = idx%24, g = sub/6, h = sub%6, b = g*64 + w;  // group same-mask blocks
    const int bh = b*6 + h;
    const unsigned short* kb  = kg + bh*10976;
    const unsigned short* vb  = vg + bh*10976;
    const unsigned short* qb  = q  + bh*10976;
    const float*          mw  = mask + w*117649;
    const unsigned short* bhp = bias + h*120736;

    for (int i=tid; i<1372; i+=256){                     // K: 343x32
        int rr=i>>2, cc=(i&3)<<3;
        *(i32x4*)&Ks[rr*40+cc] = *(const i32x4*)(kb + rr*32 + cc);
    }
    for (int i=tid; i<1372; i+=256){                     // V rows -> Vs[d][tok] transpose
        int tok=i>>2, c=(i&3)<<3;
        bf16x8 vv = *(const bf16x8*)(vb + tok*32 + c);
        #pragma unroll
        for (int j=0;j<8;++j) Vs[(c+j)*344 + tok] = (unsigned short)vv[j];
    }
    if (tid < 32) Vs[tid*344 + 343] = 0;                 // pad token column
    if (tid < 64) Vs[32*344 + tid] = 0;                  // tail for row-31 b128 overflow read
    __syncthreads();

    for (int chunk=wid; chunk<22; chunk+=4){             // 16-row Q strips, waves independent
        int qrow = chunk*16 + l15; if (qrow > 342) qrow = 342;   // stay inside this bh's q slice
        bf16x8 a = *(const bf16x8*)(qb + qrow*32 + quad*8);
        f32x4 s[22];
        #pragma unroll
        for (int t=0; t<22; ++t){
            bf16x8 bb = *(const bf16x8*)&Ks[(t*16+l15)*40 + quad*8];
            s[t] = MFMA16(a, bb, zero4());
        }
        const int row0 = chunk*16 + quad*4;
        #pragma unroll
        for (int r=0; r<4; ++r){
            int row = row0 + r; int rowc = row>342 ? 342 : row;
            const float*          mrow = mw  + rowc*343;
            const unsigned short* brow = bhp + rowc*352;
            #pragma unroll
            for (int t=0; t<22; ++t){
                int col  = t*16 + l15;
                int colc = col>342 ? 342 : col;
                s[t][r] += mrow[colc] + bf2f(brow[col]);
            }
        }
        if (l15 >= 7){                                   // columns 343..351 -> -inf
            #pragma unroll
            for (int r=0; r<4; ++r) s[21][r] = -1e30f;
        }
        f32x4 mx, sm, inv;
        #pragma unroll
        for (int r=0; r<4; ++r){
            float m = s[0][r];
            #pragma unroll
            for (int t=1; t<22; ++t) m = fmaxf(m, s[t][r]);
            mx[r] = m;
        }
        #pragma unroll
        for (int d=1; d<16; d<<=1){
            #pragma unroll
            for (int r=0; r<4; ++r) mx[r] = fmaxf(mx[r], __shfl_xor(mx[r], d));
        }
        #pragma unroll
        for (int r=0; r<4; ++r){
            float acc = 0.f;
            #pragma unroll
            for (int t=0; t<22; ++t){ float e = __expf(s[t][r]-mx[r]); s[t][r]=e; acc += e; }
            sm[r] = acc;
        }
        #pragma unroll
        for (int d=1; d<16; d<<=1){
            #pragma unroll
            for (int r=0; r<4; ++r) sm[r] += __shfl_xor(sm[r], d);
        }
        #pragma unroll
        for (int r=0; r<4; ++r) inv[r] = 1.0f / sm[r];

        f32x4 o0 = zero4(), o1 = zero4();
        unsigned short* pw0 = Pb + wid*1280;
        #pragma unroll
        for (int ks=0; ks<11; ++ks){                     // P(C-layout) -> LDS -> A-layout, 32 keys/step
            unsigned short* pw = pw0 + (ks&1)*640;
            #pragma unroll
            for (int tt=0; tt<2; ++tt){
                int t = ks*2+tt;
                #pragma unroll
                for (int r=0; r<4; ++r)
                    pw[(quad*4+r)*40 + tt*16 + l15] = f2bf(s[t][r]*inv[r]);
            }
            asm volatile("s_waitcnt lgkmcnt(0)" ::: "memory");
            bf16x8 ap = *(const bf16x8*)&pw[l15*40 + quad*8];
            bf16x8 v0 = *(const bf16x8*)&Vs[l15*344      + ks*32 + quad*8];
            bf16x8 v1 = *(const bf16x8*)&Vs[(16+l15)*344 + ks*32 + quad*8];
            o0 = MFMA16(ap, v0, o0);
            o1 = MFMA16(ap, v1, o1);
        }
        #pragma unroll
        for (int r=0; r<4; ++r){
            int nt = row0 + r;
            if (nt < 343){
                unsigned short* dst = ao + (b*343 + nt)*192 + h*32;
                dst[l15]    = f2bf(o0[r]);
                dst[16+l15] = f2bf(o1[r]);
            }
        }
    }
}

// ---------------- output projection (fp32 output) ----------------
__global__ __launch_bounds__(256) void k_proj(const unsigned short* __restrict__ ao,
                                              const unsigned short* __restrict__ pwt,
                                              const float* __restrict__ pbias,
                                              float* __restrict__ out){
    const int tid = threadIdx.x, wid = tid>>6, lane = tid&63, quad = lane>>4, l15 = lane&15;
    const int m0 = blockIdx.x*64 + wid*16;
    f32x4 acc[12];
    #pragma unroll
    for (int st=0; st<12; ++st) acc[st] = zero4();
    float bl[12];
    #pragma unroll
    for (int st=0; st<12; ++st) bl[st] = pbias[st*16 + l15];
    const unsigned short* arow = ao + (m0 + l15)*192 + quad*8;
    for (int k0=0; k0<192; k0+=32){
        bf16x8 a = *(const bf16x8*)(arow + k0);
        #pragma unroll
        for (int st=0; st<12; ++st){
            bf16x8 bb = *(const bf16x8*)(pwt + (st*16+l15)*192 + k0 + quad*8);
            acc[st] = MFMA16(a, bb, acc[st]);
        }
    }
    #pragma unroll
    for (int r=0; r<4; ++r){
        int tm = m0 + quad*4 + r;
        #pragma unroll
        for (int st=0; st<12; ++st)
            out[tm*192 + st*16 + l15] = acc[st][r] + bl[st];
    }
}

extern "C" void kernel_launch(void* const* d_in, const int* in_sizes, int n_in,
                              void* d_out, int out_size, void* d_ws, size_t ws_size,
                              hipStream_t stream){
    const float* x     = (const float*)d_in[0];
    const float* mask  = (const float*)d_in[1];
    const float* qkv_w = (const float*)d_in[2];
    const float* rpb   = (const float*)d_in[3];
    const float* projw = (const float*)d_in[4];
    const float* projb = (const float*)d_in[5];
    float* out = (float*)d_out;
    unsigned short* ws  = (unsigned short*)d_ws;

    unsigned short* wt   = ws;                 // 110592
    unsigned short* pwt  = wt   + 110592;      // 36864
    unsigned short* bias = pwt  + 36864;       // 724416
    unsigned short* q    = bias + 724416;      // 16859136
    unsigned short* k    = q    + 16859136;    // 16859136
    unsigned short* v    = k    + 16859136;    // 16859136
    unsigned short* ao   = v    + 16859136;    // 16859136   total ~136.5 MB

    hipLaunchKernelGGL(k_prep_wt,   dim3(432),  dim3(256), 0, stream, qkv_w, wt);
    hipLaunchKernelGGL(k_prep_pwt,  dim3(144),  dim3(256), 0, stream, projw, pwt);
    hipLaunchKernelGGL(k_prep_bias, dim3(2830), dim3(256), 0, stream, rpb, bias);
    hipLaunchKernelGGL(k_qkv,       dim3(2058), dim3(256), 0, stream, x, wt, q, k, v);
    hipLaunchKernelGGL(k_attn,      dim3(1536), dim3(256), 0, stream, q, k, v, mask, bias, ao);
    hipLaunchKernelGGL(k_proj,      dim3(1372), dim3(256), 0, stream, ao, pwt, projb, out);
}